// Round 1
// baseline (2778.975 us; speedup 1.0000x reference)
//
#include <hip/hip_runtime.h>
#include <cstddef>

#define BN_EPS 1e-5f

// ---------------------------------------------------------------------------
// Sparse conv: out[j, co] = sum_k sum_ci x[map[k][j], ci] * W[k, ci, co]
// x may be a concat of two tensors xA (CINA ch) and xB (CIN-CINA ch).
// Layout: one output row per row-group of COUT threads; block = COUT*ROWS.
// For COUT >= 64 the map entry is wave-uniform -> readfirstlane scalarizes it.
// ---------------------------------------------------------------------------
template<int CIN, int CINA, int COUT, int ROWS>
__global__ __launch_bounds__(COUT * ROWS)
void sconv_kernel(const float* __restrict__ xA, const float* __restrict__ xB,
                  const float* __restrict__ W, const int* __restrict__ map,
                  int Nout, float* __restrict__ out)
{
    constexpr int CINB = CIN - CINA;
    const int tid = threadIdx.x;
    const int co  = tid % COUT;
    const int r   = tid / COUT;
    const int j   = blockIdx.x * ROWS + r;
    if (j >= Nout) return;

    float acc = 0.f;
    #pragma unroll 1
    for (int k = 0; k < 27; ++k) {
        int m = map[(size_t)k * Nout + j];
        if constexpr (COUT >= 64) {
            // whole wave shares one output row -> m is wave-uniform
            m = __builtin_amdgcn_readfirstlane(m);
        }
        if (m < 0) continue;

        const float* wk = W + ((size_t)k * CIN) * COUT + co;
        const float* xa = xA + (size_t)m * CINA;
        #pragma unroll
        for (int ci = 0; ci < CINA; ++ci)
            acc = fmaf(xa[ci], wk[(size_t)ci * COUT], acc);

        if constexpr (CINB > 0) {
            const float* xb  = xB + (size_t)m * CINB;
            const float* wkb = wk + (size_t)CINA * COUT;
            #pragma unroll
            for (int ci = 0; ci < CINB; ++ci)
                acc = fmaf(xb[ci], wkb[(size_t)ci * COUT], acc);
        }
    }
    out[(size_t)j * COUT + co] = acc;
}

// ---------------------------------------------------------------------------
// Final conv: COUT=2, thread per output row.  x = concat(d1[*,64], s1[*,32]).
// ---------------------------------------------------------------------------
__global__ void conv0t_kernel(const float* __restrict__ d1,
                              const float* __restrict__ s1,
                              const float* __restrict__ W /*[27,96,2]*/,
                              const int* __restrict__ map, int N0,
                              float* __restrict__ out /*[N0,2]*/)
{
    const int j = blockIdx.x * blockDim.x + threadIdx.x;
    if (j >= N0) return;
    float a0 = 0.f, a1 = 0.f;
    #pragma unroll 1
    for (int k = 0; k < 27; ++k) {
        const int m = map[(size_t)k * N0 + j];
        if (m < 0) continue;
        const float* w  = W + (size_t)k * 96 * 2;
        const float* xa = d1 + (size_t)m * 64;
        #pragma unroll
        for (int ci = 0; ci < 64; ++ci) {
            a0 = fmaf(xa[ci], w[ci * 2 + 0], a0);
            a1 = fmaf(xa[ci], w[ci * 2 + 1], a1);
        }
        const float* xb = s1 + (size_t)m * 32;
        const float* wb = w + 64 * 2;
        #pragma unroll
        for (int ci = 0; ci < 32; ++ci) {
            a0 = fmaf(xb[ci], wb[ci * 2 + 0], a0);
            a1 = fmaf(xb[ci], wb[ci * 2 + 1], a1);
        }
    }
    out[(size_t)j * 2 + 0] = a0;
    out[(size_t)j * 2 + 1] = a1;
}

// ---------------------------------------------------------------------------
// BN pass 1: per-channel sum and sum-of-squares -> atomicAdd into sums[2*C]
// ---------------------------------------------------------------------------
template<int C>
__global__ __launch_bounds__(256)
void bn_reduce_kernel(const float* __restrict__ x, int N,
                      float* __restrict__ sums)
{
    constexpr int RG = 256 / C;  // rows handled concurrently per block
    const int tid = threadIdx.x;
    const int c   = tid % C;
    const int rg  = tid / C;
    float s = 0.f, s2 = 0.f;
    for (int j = blockIdx.x * RG + rg; j < N; j += gridDim.x * RG) {
        const float v = x[(size_t)j * C + c];
        s += v;
        s2 += v * v;
    }
    __shared__ float sh[2 * 256];
    sh[tid] = s;
    sh[256 + tid] = s2;
    __syncthreads();
    for (int stride = 128; stride >= C; stride >>= 1) {
        if (tid < stride) {
            sh[tid] += sh[tid + stride];
            sh[256 + tid] += sh[256 + tid + stride];
        }
        __syncthreads();
    }
    if (tid < C) {
        atomicAdd(&sums[c], sh[tid]);
        atomicAdd(&sums[C + c], sh[256 + tid]);
    }
}

// ---------------------------------------------------------------------------
// BN pass 2: x = relu((x - mu) * rsqrt(var + eps) * g + b), in place
// ---------------------------------------------------------------------------
template<int C>
__global__ __launch_bounds__(256)
void bn_apply_kernel(float* __restrict__ x, int N,
                     const float* __restrict__ sums,
                     const float* __restrict__ g, const float* __restrict__ b)
{
    const int tid = blockIdx.x * blockDim.x + threadIdx.x;
    const int c = tid % C;
    const float invN = 1.0f / (float)N;
    const float mean = sums[c] * invN;
    float var = sums[C + c] * invN - mean * mean;
    var = fmaxf(var, 0.f);
    const float sc = g[c] * rsqrtf(var + BN_EPS);
    const float sh = b[c] - mean * sc;
    const int rows_stride = (gridDim.x * blockDim.x) / C;
    for (int j = tid / C; j < N; j += rows_stride) {
        const size_t i = (size_t)j * C + c;
        const float v = fmaf(x[i], sc, sh);
        x[i] = v > 0.f ? v : 0.f;
    }
}

// ---------------------------------------------------------------------------
extern "C" void kernel_launch(void* const* d_in, const int* in_sizes, int n_in,
                              void* d_out, int out_size, void* d_ws, size_t ws_size,
                              hipStream_t stream)
{
    const float* feats = (const float*)d_in[0];
    const float* W0  = (const float*)d_in[1];
    const float* g0  = (const float*)d_in[2];
    const float* b0  = (const float*)d_in[3];
    const float* W1  = (const float*)d_in[4];
    const float* g1  = (const float*)d_in[5];
    const float* b1  = (const float*)d_in[6];
    const float* W2  = (const float*)d_in[7];
    const float* g2  = (const float*)d_in[8];
    const float* b2  = (const float*)d_in[9];
    const float* W2t = (const float*)d_in[10];
    const float* g2t = (const float*)d_in[11];
    const float* b2t = (const float*)d_in[12];
    const float* W1t = (const float*)d_in[13];
    const float* g1t = (const float*)d_in[14];
    const float* b1t = (const float*)d_in[15];
    const float* W0t = (const float*)d_in[16];
    const int* map0  = (const int*)d_in[17];
    const int* map1  = (const int*)d_in[18];
    const int* map2  = (const int*)d_in[19];
    const int* map2t = (const int*)d_in[20];
    const int* map1t = (const int*)d_in[21];
    const int* map0t = (const int*)d_in[22];

    const int N0 = in_sizes[0] / 16;
    const int N1 = in_sizes[18] / 27;
    const int N2 = in_sizes[19] / 27;

    float* ws = (float*)d_ws;
    float* y0 = ws;                      // [N0,32]  s1
    float* y1 = y0 + (size_t)N0 * 32;    // [N1,64]  s2
    float* y2 = y1 + (size_t)N1 * 64;    // [N2,128] s4
    float* y3 = y2 + (size_t)N2 * 128;   // [N1,64]  d2
    float* y4 = y3 + (size_t)N1 * 64;    // [N0,64]  d1
    float* sums  = y4 + (size_t)N0 * 64; // 704 floats of BN accumulators
    float* sums0 = sums;        // 2*32
    float* sums1 = sums + 64;   // 2*64
    float* sums2 = sums + 192;  // 2*128
    float* sums3 = sums + 448;  // 2*64
    float* sums4 = sums + 576;  // 2*64

    hipMemsetAsync(sums, 0, 704 * sizeof(float), stream);

    // block0: feats[N0,16] -> y0[N0,32]
    sconv_kernel<16, 16, 32, 8><<<(N0 + 7) / 8, 256, 0, stream>>>(
        feats, nullptr, W0, map0, N0, y0);
    bn_reduce_kernel<32><<<512, 256, 0, stream>>>(y0, N0, sums0);
    bn_apply_kernel<32><<<512, 256, 0, stream>>>(y0, N0, sums0, g0, b0);

    // block1: s1[N0,32] -> y1[N1,64]
    sconv_kernel<32, 32, 64, 4><<<(N1 + 3) / 4, 256, 0, stream>>>(
        y0, nullptr, W1, map1, N1, y1);
    bn_reduce_kernel<64><<<512, 256, 0, stream>>>(y1, N1, sums1);
    bn_apply_kernel<64><<<512, 256, 0, stream>>>(y1, N1, sums1, g1, b1);

    // block2: s2[N1,64] -> y2[N2,128]
    sconv_kernel<64, 64, 128, 2><<<(N2 + 1) / 2, 256, 0, stream>>>(
        y1, nullptr, W2, map2, N2, y2);
    bn_reduce_kernel<128><<<512, 256, 0, stream>>>(y2, N2, sums2);
    bn_apply_kernel<128><<<512, 256, 0, stream>>>(y2, N2, sums2, g2, b2);

    // block2_tr: s4[N2,128] -> y3[N1,64]
    sconv_kernel<128, 128, 64, 4><<<(N1 + 3) / 4, 256, 0, stream>>>(
        y2, nullptr, W2t, map2t, N1, y3);
    bn_reduce_kernel<64><<<512, 256, 0, stream>>>(y3, N1, sums3);
    bn_apply_kernel<64><<<512, 256, 0, stream>>>(y3, N1, sums3, g2t, b2t);

    // block1_tr: concat(d2,s2)[N1,128] -> y4[N0,64]
    sconv_kernel<128, 64, 64, 4><<<(N0 + 3) / 4, 256, 0, stream>>>(
        y3, y1, W1t, map1t, N0, y4);
    bn_reduce_kernel<64><<<512, 256, 0, stream>>>(y4, N0, sums4);
    bn_apply_kernel<64><<<512, 256, 0, stream>>>(y4, N0, sums4, g1t, b1t);

    // block0_tr: concat(d1,s1)[N0,96] -> out[N0,2]
    conv0t_kernel<<<(N0 + 255) / 256, 256, 0, stream>>>(
        y4, y0, W0t, map0t, N0, (float*)d_out);
}

// Round 2
// 2084.921 us; speedup vs baseline: 1.3329x; 1.3329x over previous
//
#include <hip/hip_runtime.h>
#include <cstddef>

#define BN_EPS 1e-5f

// ---------------------------------------------------------------------------
// Generic sparse conv for COUT in {64,128}: one output row per wave-row-slot.
// Block = 256 threads = 4 waves; each wave handles R consecutive output rows.
// Lane co = lane (+64 for CPL=2). Map entries prefetched lane-parallel, then
// broadcast via shfl+readfirstlane -> wave-uniform scalar branches.
// W fragments are loaded once per k and reused across the R rows.
// x may be a concat of xA (CINA ch) and xB (CIN-CINA ch).
// ---------------------------------------------------------------------------
template<int CIN, int CINA, int COUT, int R>
__global__ __launch_bounds__(256)
void sconv_big(const float* __restrict__ xA, const float* __restrict__ xB,
               const float* __restrict__ W, const int* __restrict__ map,
               int Nout, float* __restrict__ out)
{
    constexpr int CINB = CIN - CINA;
    constexpr int CPL  = COUT / 64;      // channels per lane (1 or 2)
    const int lane = threadIdx.x & 63;
    const int wave = threadIdx.x >> 6;
    const int row0 = (blockIdx.x * 4 + wave) * R;

    // Prefetch all 27 map entries for each of this wave's R rows.
    int mk[R];
    #pragma unroll
    for (int r = 0; r < R; ++r) {
        const int j = row0 + r;
        mk[r] = (lane < 27 && j < Nout) ? map[(size_t)lane * Nout + j] : -1;
    }

    float acc[R][CPL];
    #pragma unroll
    for (int r = 0; r < R; ++r)
        #pragma unroll
        for (int c = 0; c < CPL; ++c) acc[r][c] = 0.f;

    for (int k = 0; k < 27; ++k) {
        int m[R];
        bool any = false;
        #pragma unroll
        for (int r = 0; r < R; ++r) {
            m[r] = __builtin_amdgcn_readfirstlane(__shfl(mk[r], k));
            any |= (m[r] >= 0);
        }
        if (!any) continue;

        const float* Wk = W + (size_t)k * CIN * COUT;

        #pragma unroll 4
        for (int ci = 0; ci < CIN; ci += 4) {
            float w[4][CPL];
            #pragma unroll
            for (int u = 0; u < 4; ++u)
                #pragma unroll
                for (int c = 0; c < CPL; ++c)
                    w[u][c] = Wk[(size_t)(ci + u) * COUT + c * 64 + lane];

            #pragma unroll
            for (int r = 0; r < R; ++r) {
                if (m[r] < 0) continue;   // wave-uniform scalar branch
                const float* xr = (ci < CINA)
                    ? (xA + (size_t)m[r] * CINA + ci)
                    : (xB + (size_t)m[r] * CINB + (ci - CINA));
                const float4 xv = *(const float4*)xr;
                #pragma unroll
                for (int c = 0; c < CPL; ++c) {
                    acc[r][c] = fmaf(xv.x, w[0][c], acc[r][c]);
                    acc[r][c] = fmaf(xv.y, w[1][c], acc[r][c]);
                    acc[r][c] = fmaf(xv.z, w[2][c], acc[r][c]);
                    acc[r][c] = fmaf(xv.w, w[3][c], acc[r][c]);
                }
            }
        }
    }

    #pragma unroll
    for (int r = 0; r < R; ++r) {
        const int j = row0 + r;
        if (j < Nout) {
            #pragma unroll
            for (int c = 0; c < CPL; ++c)
                out[(size_t)j * COUT + c * 64 + lane] = acc[r][c];
        }
    }
}

// ---------------------------------------------------------------------------
// conv0: CIN=16, COUT=32. One row per half-wave; block 256 = 8 rows.
// ---------------------------------------------------------------------------
__global__ __launch_bounds__(256)
void sconv0(const float* __restrict__ x, const float* __restrict__ W,
            const int* __restrict__ map, int N, float* __restrict__ out)
{
    const int tid  = threadIdx.x;
    const int lane = tid & 63;
    const int l32  = tid & 31;
    const int co   = l32;
    const int j    = blockIdx.x * 8 + (tid >> 5);

    int mk = (l32 < 27 && j < N) ? map[(size_t)l32 * N + j] : -1;

    float a0 = 0.f, a1 = 0.f, a2 = 0.f, a3 = 0.f;
    for (int k = 0; k < 27; ++k) {
        const int m = __shfl(mk, (lane & 32) + k);
        if (m < 0) continue;
        const float* xr = x + (size_t)m * 16;
        const float* wk = W + (size_t)k * 16 * 32 + co;
        #pragma unroll
        for (int ci = 0; ci < 16; ci += 4) {
            const float4 xv = *(const float4*)(xr + ci);
            a0 = fmaf(xv.x, wk[(ci + 0) * 32], a0);
            a1 = fmaf(xv.y, wk[(ci + 1) * 32], a1);
            a2 = fmaf(xv.z, wk[(ci + 2) * 32], a2);
            a3 = fmaf(xv.w, wk[(ci + 3) * 32], a3);
        }
    }
    if (j < N) out[(size_t)j * 32 + co] = (a0 + a1) + (a2 + a3);
}

// ---------------------------------------------------------------------------
// conv0t: x = concat(d1[*,64], s1[*,32]), COUT=2. 32 lanes cooperate per row:
// lane handles ci = {l32, l32+32, l32+64}; shfl-reduce at the end.
// ---------------------------------------------------------------------------
__global__ __launch_bounds__(256)
void sconv0t(const float* __restrict__ d1, const float* __restrict__ s1,
             const float* __restrict__ W /*[27,96,2]*/,
             const int* __restrict__ map, int N, float* __restrict__ out)
{
    const int tid  = threadIdx.x;
    const int lane = tid & 63;
    const int l32  = tid & 31;
    const int j    = blockIdx.x * 8 + (tid >> 5);

    int mk = (l32 < 27 && j < N) ? map[(size_t)l32 * N + j] : -1;

    float a0 = 0.f, a1 = 0.f;
    for (int k = 0; k < 27; ++k) {
        const int m = __shfl(mk, (lane & 32) + k);
        if (m < 0) continue;
        const float* w = W + (size_t)k * 96 * 2;
        const float x0 = d1[(size_t)m * 64 + l32];
        const float x1 = d1[(size_t)m * 64 + l32 + 32];
        const float x2 = s1[(size_t)m * 32 + l32];
        a0 = fmaf(x0, w[l32 * 2 + 0], a0);
        a1 = fmaf(x0, w[l32 * 2 + 1], a1);
        a0 = fmaf(x1, w[(l32 + 32) * 2 + 0], a0);
        a1 = fmaf(x1, w[(l32 + 32) * 2 + 1], a1);
        a0 = fmaf(x2, w[(l32 + 64) * 2 + 0], a0);
        a1 = fmaf(x2, w[(l32 + 64) * 2 + 1], a1);
    }
    #pragma unroll
    for (int off = 1; off < 32; off <<= 1) {
        a0 += __shfl_xor(a0, off, 32);
        a1 += __shfl_xor(a1, off, 32);
    }
    if (l32 == 0 && j < N) {
        out[(size_t)j * 2 + 0] = a0;
        out[(size_t)j * 2 + 1] = a1;
    }
}

// ---------------------------------------------------------------------------
// BN pass 1: per-channel sum and sum-of-squares -> atomicAdd into sums[2*C]
// ---------------------------------------------------------------------------
template<int C>
__global__ __launch_bounds__(256)
void bn_reduce_kernel(const float* __restrict__ x, int N,
                      float* __restrict__ sums)
{
    constexpr int RG = 256 / C;
    const int tid = threadIdx.x;
    const int c   = tid % C;
    const int rg  = tid / C;
    float s = 0.f, s2 = 0.f;
    for (int j = blockIdx.x * RG + rg; j < N; j += gridDim.x * RG) {
        const float v = x[(size_t)j * C + c];
        s += v;
        s2 += v * v;
    }
    __shared__ float sh[2 * 256];
    sh[tid] = s;
    sh[256 + tid] = s2;
    __syncthreads();
    for (int stride = 128; stride >= C; stride >>= 1) {
        if (tid < stride) {
            sh[tid] += sh[tid + stride];
            sh[256 + tid] += sh[256 + tid + stride];
        }
        __syncthreads();
    }
    if (tid < C) {
        atomicAdd(&sums[c], sh[tid]);
        atomicAdd(&sums[C + c], sh[256 + tid]);
    }
}

// ---------------------------------------------------------------------------
// BN pass 2: x = relu((x - mu) * rsqrt(var + eps) * g + b), in place
// ---------------------------------------------------------------------------
template<int C>
__global__ __launch_bounds__(256)
void bn_apply_kernel(float* __restrict__ x, int N,
                     const float* __restrict__ sums,
                     const float* __restrict__ g, const float* __restrict__ b)
{
    const int tid = blockIdx.x * blockDim.x + threadIdx.x;
    const int c = tid % C;
    const float invN = 1.0f / (float)N;
    const float mean = sums[c] * invN;
    float var = sums[C + c] * invN - mean * mean;
    var = fmaxf(var, 0.f);
    const float sc = g[c] * rsqrtf(var + BN_EPS);
    const float sh = b[c] - mean * sc;
    const int rows_stride = (gridDim.x * blockDim.x) / C;
    for (int j = tid / C; j < N; j += rows_stride) {
        const size_t i = (size_t)j * C + c;
        const float v = fmaf(x[i], sc, sh);
        x[i] = v > 0.f ? v : 0.f;
    }
}

// ---------------------------------------------------------------------------
extern "C" void kernel_launch(void* const* d_in, const int* in_sizes, int n_in,
                              void* d_out, int out_size, void* d_ws, size_t ws_size,
                              hipStream_t stream)
{
    const float* feats = (const float*)d_in[0];
    const float* W0  = (const float*)d_in[1];
    const float* g0  = (const float*)d_in[2];
    const float* b0  = (const float*)d_in[3];
    const float* W1  = (const float*)d_in[4];
    const float* g1  = (const float*)d_in[5];
    const float* b1  = (const float*)d_in[6];
    const float* W2  = (const float*)d_in[7];
    const float* g2  = (const float*)d_in[8];
    const float* b2  = (const float*)d_in[9];
    const float* W2t = (const float*)d_in[10];
    const float* g2t = (const float*)d_in[11];
    const float* b2t = (const float*)d_in[12];
    const float* W1t = (const float*)d_in[13];
    const float* g1t = (const float*)d_in[14];
    const float* b1t = (const float*)d_in[15];
    const float* W0t = (const float*)d_in[16];
    const int* map0  = (const int*)d_in[17];
    const int* map1  = (const int*)d_in[18];
    const int* map2  = (const int*)d_in[19];
    const int* map2t = (const int*)d_in[20];
    const int* map1t = (const int*)d_in[21];
    const int* map0t = (const int*)d_in[22];

    const int N0 = in_sizes[0] / 16;
    const int N1 = in_sizes[18] / 27;
    const int N2 = in_sizes[19] / 27;

    float* ws = (float*)d_ws;
    float* y0 = ws;                      // [N0,32]  s1
    float* y1 = y0 + (size_t)N0 * 32;    // [N1,64]  s2
    float* y2 = y1 + (size_t)N1 * 64;    // [N2,128] s4
    float* y3 = y2 + (size_t)N2 * 128;   // [N1,64]  d2
    float* y4 = y3 + (size_t)N1 * 64;    // [N0,64]  d1
    float* sums  = y4 + (size_t)N0 * 64; // BN accumulators (704 floats)
    float* sums0 = sums;        // 2*32
    float* sums1 = sums + 64;   // 2*64
    float* sums2 = sums + 192;  // 2*128
    float* sums3 = sums + 448;  // 2*64
    float* sums4 = sums + 576;  // 2*64

    hipMemsetAsync(sums, 0, 704 * sizeof(float), stream);

    // block0: feats[N0,16] -> y0[N0,32]
    sconv0<<<(N0 + 7) / 8, 256, 0, stream>>>(feats, W0, map0, N0, y0);
    bn_reduce_kernel<32><<<512, 256, 0, stream>>>(y0, N0, sums0);
    bn_apply_kernel<32><<<512, 256, 0, stream>>>(y0, N0, sums0, g0, b0);

    // block1: s1[N0,32] -> y1[N1,64]   (R=4 -> 16 rows/block)
    sconv_big<32, 32, 64, 4><<<(N1 + 15) / 16, 256, 0, stream>>>(
        y0, nullptr, W1, map1, N1, y1);
    bn_reduce_kernel<64><<<512, 256, 0, stream>>>(y1, N1, sums1);
    bn_apply_kernel<64><<<512, 256, 0, stream>>>(y1, N1, sums1, g1, b1);

    // block2: s2[N1,64] -> y2[N2,128]  (R=2 -> 8 rows/block)
    sconv_big<64, 64, 128, 2><<<(N2 + 7) / 8, 256, 0, stream>>>(
        y1, nullptr, W2, map2, N2, y2);
    bn_reduce_kernel<128><<<512, 256, 0, stream>>>(y2, N2, sums2);
    bn_apply_kernel<128><<<512, 256, 0, stream>>>(y2, N2, sums2, g2, b2);

    // block2_tr: s4[N2,128] -> y3[N1,64]  (R=4 -> 16 rows/block)
    sconv_big<128, 128, 64, 4><<<(N1 + 15) / 16, 256, 0, stream>>>(
        y2, nullptr, W2t, map2t, N1, y3);
    bn_reduce_kernel<64><<<512, 256, 0, stream>>>(y3, N1, sums3);
    bn_apply_kernel<64><<<512, 256, 0, stream>>>(y3, N1, sums3, g2t, b2t);

    // block1_tr: concat(d2,s2)[N1,128] -> y4[N0,64]  (R=4)
    sconv_big<128, 64, 64, 4><<<(N0 + 15) / 16, 256, 0, stream>>>(
        y3, y1, W1t, map1t, N0, y4);
    bn_reduce_kernel<64><<<512, 256, 0, stream>>>(y4, N0, sums4);
    bn_apply_kernel<64><<<512, 256, 0, stream>>>(y4, N0, sums4, g1t, b1t);

    // block0_tr: concat(d1,s1)[N0,96] -> out[N0,2]
    sconv0t<<<(N0 + 7) / 8, 256, 0, stream>>>(y4, y0, W0t, map0t, N0,
                                              (float*)d_out);
}